// Round 1
// baseline (361.399 us; speedup 1.0000x reference)
//
#include <hip/hip_runtime.h>
#include <stdint.h>

#define EPSV 1e-5f

typedef int v4i __attribute__((ext_vector_type(4)));

__device__ __forceinline__ v4i mfma16(v4i a, v4i b, v4i c) {
    return __builtin_amdgcn_mfma_i32_16x16x64_i8(a, b, c, 0, 0, 0);
}

// epilogue first stage: BN + ReLU-u4 quant -> r index in [0,15].
// (bit-exact same float sequence as before; second quant is a 16-entry LUT)
__device__ __forceinline__ int q_r(int s, float fscale, float inv, float beta,
                                   float s_relu)
{
#pragma clang fp contract(off)
    float y = (float)s * fscale;
    y = y * inv;
    y = y + beta;
    float r = rintf(y / s_relu);
    r = fminf(fmaxf(r, 0.f), 15.f);
    return (int)r;
}

// ---------------------------------------------------------------------------
// Per-tensor weight max-abs. grid (16, 9)
// ---------------------------------------------------------------------------
struct WPtrs { const float* w[9]; int n[9]; };

__global__ __launch_bounds__(256) void k_wmax(WPtrs a, unsigned* __restrict__ smax)
{
    const int t = blockIdx.y;
    const int n = a.n[t];
    const float* w = a.w[t];
    float m = 0.f;
    for (int i = blockIdx.x * 256 + threadIdx.x; i < n; i += 16 * 256)
        m = fmaxf(m, fabsf(w[i]));
#pragma unroll
    for (int off = 32; off > 0; off >>= 1) m = fmaxf(m, __shfl_down(m, off));
    __shared__ float red[4];
    if ((threadIdx.x & 63) == 0) red[threadIdx.x >> 6] = m;
    __syncthreads();
    if (threadIdx.x == 0) {
        m = fmaxf(fmaxf(red[0], red[1]), fmaxf(red[2], red[3]));
        atomicMax(smax + t, __float_as_uint(m));
    }
}

// ---------------------------------------------------------------------------
// Pack kernel:
//  seg B    : conv weights -> MFMA B-fragment order (52992 dwords)
//  seg HEADF: head weights -> MFMA B-fragment order, NT=3 (768 dwords)
//  seg BN   : inv/beta (8*128 floats) + requant LUTs (8*16 + 16 int8)
// ---------------------------------------------------------------------------
struct PackArgs {
    const float* w[9];
    const float* bn[8];
    const float* sc;
    const unsigned* smax;
    int* qw;
    float* bnp;
    int8_t* lut;
};

#define NB_B    207
#define NB_HEAD 3
#define NB_BN   3

__global__ __launch_bounds__(256) void k_pack(PackArgs a)
{
#pragma clang fp contract(off)
    const int blk = blockIdx.x;
    if (blk < NB_B) {
        const int u = blk * 256 + threadIdx.x;   // 0..52991 (exact)
        const int bcum[9] = {0, 256, 1792, 6912, 16128, 25344, 34560, 43776, 52992};
        const int CIGA[8] = {1, 4, 8, 16, 16, 16, 16, 16};
        const int COA[8]  = {16, 32, 64, 64, 64, 64, 64, 64};
        const int NTA[8]  = {1, 2, 4, 4, 4, 4, 4, 4};
        const int CINA[8] = {3, 16, 32, 64, 64, 64, 64, 64};
        int L = 0;
        while (u >= bcum[L + 1]) ++L;
        const int rem = u - bcum[L];
        const int d = rem & 3;
        const int lane = (rem >> 2) & 63;
        const int gnt = rem >> 8;
        const int NT = NTA[L];
        const int nt = gnt % NT;
        const int g = gnt / NT;
        const int CIG = CIGA[L], CIN = CINA[L], CO = COA[L];
        const int TG = 16 / CIG;
        const int n = nt * 16 + (lane & 15);
        const float s = __uint_as_float(a.smax[L]) / 7.0f;
        const float* w = a.w[L];
        unsigned dw = 0;
        for (int jb = 0; jb < 4; ++jb) {
            const int k = 16 * (lane >> 4) + 4 * d + jb;
            const int tap = g * TG + k / (4 * CIG);
            const int ci = k % (4 * CIG);
            int qv = 0;
            if (tap < 9 && ci < CIN && n < CO) {
                float rr = rintf(w[(n * CIN + ci) * 9 + tap] / s);
                rr = fminf(fmaxf(rr, -7.f), 7.f);
                qv = (int)rr;
            }
            dw |= ((unsigned)(qv & 0xff)) << (8 * jb);
        }
        a.qw[u] = (int)dw;
    } else if (blk < NB_B + NB_HEAD) {
        const int uh = (blk - NB_B) * 256 + threadIdx.x;  // 0..767 (exact)
        const int d = uh & 3;
        const int lane = (uh >> 2) & 63;
        const int nt = uh >> 8;                            // 0..2
        const int n = nt * 16 + (lane & 15);
        const float s = __uint_as_float(a.smax[8]) / 7.0f;
        const float* w = a.w[8];
        unsigned dw = 0;
        for (int jb = 0; jb < 4; ++jb) {
            const int ci = 16 * (lane >> 4) + 4 * d + jb;   // K=64 = cin
            int qv = 0;
            if (n < 36) {
                float rr = rintf(w[n * 64 + ci] / s);
                rr = fminf(fmaxf(rr, -7.f), 7.f);
                qv = (int)rr;
            }
            dw |= ((unsigned)(qv & 0xff)) << (8 * jb);
        }
        a.qw[52992 + uh] = (int)dw;
    } else {
        const int id = (blk - NB_B - NB_HEAD) * 256 + threadIdx.x;
        if (id < 512) {
            const int l = id >> 6, c = id & 63;
            const int C[8] = {16, 32, 64, 64, 64, 64, 64, 64};
            if (c < C[l]) {
                const float* bn = a.bn[l];
                const int Cl = C[l];
                float g = bn[c], b = bn[Cl + c], m = bn[2 * Cl + c], v = bn[3 * Cl + c];
                float inv = g / sqrtf(v + EPSV);
                float mi = m * inv;
                a.bnp[l * 128 + c] = inv;
                a.bnp[l * 128 + 64 + c] = b - mi;
            }
        } else if (id < 656) {
            // requant LUTs. l=0..7: relu-u4 r -> next-layer signed code
            //               l=8   : conv0 input double-quant, idx = r0+8
            const int j = id - 512;
            const int l = j >> 4, r = j & 15;
            float code;
            if (l < 8) {
                const float s_relu = a.sc[10 + l];
                const float s_next = (l < 7) ? a.sc[2 + l] : a.sc[9];
                const float v = (float)r * s_relu;          // bit-exact: r*s_relu
                code = fminf(fmaxf(rintf(v / s_next), -8.f), 7.f);
            } else {
                const float v = (float)(r - 8) * a.sc[0];
                code = fminf(fmaxf(rintf(v / a.sc[1]), -8.f), 7.f);
            }
            a.lut[j] = (int8_t)(int)code;
        }
    }
}

// ---------------------------------------------------------------------------
// L0 fused: fake-quant of fp32 x (NCHW) during tile staging (1 div + LUT) +
// MFMA conv 3->16ch + BN/ReLU-quant(LUT)/pool. out NHWC [16][160][320][16].
// grid (10, 40, 16); tile 10x66 px, CIG=1.
// ---------------------------------------------------------------------------
__global__ __launch_bounds__(256) void k_conv0(
    const float* __restrict__ x, int8_t* __restrict__ out,
    const int* __restrict__ bfrag, const float* __restrict__ scales,
    const unsigned* __restrict__ smax, const float* __restrict__ bnp,
    const int8_t* __restrict__ luts)
{
#pragma clang fp contract(off)
    __shared__ int tile[660];        // 10 * 66
    __shared__ float bnl[128];
    __shared__ int8_t lc[32];        // [0..15] layer0 epi lut, [16..31] input lut

    const int b = blockIdx.z;
    const int py0 = blockIdx.y * 4;
    const int px0 = blockIdx.x * 32;
    const int ty0 = 2 * py0 - 1;
    const int tx0 = 2 * px0 - 1;
    const float s0 = scales[0];

    if (threadIdx.x < 16) lc[threadIdx.x] = luts[threadIdx.x];
    else if (threadIdx.x < 32) lc[threadIdx.x] = luts[128 + threadIdx.x - 16];
    if (threadIdx.x < 128) bnl[threadIdx.x] = bnp[threadIdx.x];
    __syncthreads();

    for (int i = threadIdx.x; i < 660; i += 256) {
        const int ly = i / 66;
        const int lx = i - ly * 66;
        const int gy = ty0 + ly, gx = tx0 + lx;
        int v = 0;
        if ((unsigned)gy < 320u && (unsigned)gx < 640u) {
#pragma unroll
            for (int ci = 0; ci < 3; ++ci) {
                float xv = x[((size_t)(b * 3 + ci) * 320 + gy) * 640 + gx];
                float r = rintf(xv / s0);
                r = fminf(fmaxf(r, -8.f), 7.f);
                v |= ((int)lc[16 + (int)r + 8] & 0xff) << (8 * ci);
            }
        }
        tile[i] = v;
    }

    const int lane = threadIdx.x & 63;
    const int wv = threadIdx.x >> 6;
    const v4i bfv = *(const v4i*)&bfrag[lane * 4];
    __syncthreads();

    const int q = lane >> 4;
    const int m = lane & 15;
    const int px_sub = m >> 2;
    const int op = m & 3;
    const int lyb = 2 * wv + (op >> 1);
    const int lxb0 = 2 * px_sub + (op & 1);

    const float sw = __uint_as_float(smax[0]) / 7.0f;
    const float fscale = scales[1] * sw;
    const float s_relu = scales[10];
    const float inv = bnl[m];
    const float beta = bnl[64 + m];
    const int py = py0 + wv;

    for (int xs = 0; xs < 8; ++xs) {
        v4i af;
#pragma unroll
        for (int d = 0; d < 4; ++d) {
            int t = 4 * q + d; t = min(t, 8);
            const int ky = (t * 11) >> 5;
            const int kx = t - 3 * ky;
            af[d] = tile[(lyb + ky) * 66 + 8 * xs + lxb0 + kx];
        }
        v4i acc = mfma16(af, bfv, (v4i){0, 0, 0, 0});
        const int px = px0 + 4 * xs + q;
        const int s = max(max(acc[0], acc[1]), max(acc[2], acc[3]));
        const int ri = q_r(s, fscale, inv, beta, s_relu);
        out[((size_t)((b * 160 + py) * 320 + px)) * 16 + m] = lc[ri];
    }
}

// ---------------------------------------------------------------------------
// MFMA pool-conv block (L1..L3). NHWC int8 in/out. B fragments preloaded to
// regs when small, else staged to LDS (L2: 20KB, L3: 36KB). LUT requant.
// ---------------------------------------------------------------------------
template <int CIG, int CO, int H, int W, int XL>
__global__ __launch_bounds__(256) void k_mconv(
    const int8_t* __restrict__ in, int8_t* __restrict__ out,
    const int* __restrict__ bfrag, const float* __restrict__ scales,
    const unsigned* __restrict__ smax, const float* __restrict__ bnp,
    const int8_t* __restrict__ luts, int layer, int sin_idx, int srelu_idx)
{
#pragma clang fp contract(off)
    constexpr int NT = CO / 16;
    constexpr int TG = 16 / CIG;              // taps per K=64 group
    constexpr int NG = (9 + TG - 1) / TG;     // K groups
    constexpr int TLH = 2 * 4 + 2;            // NROWS=4, stride 2
    constexpr int TLW = 2 * 4 * XL + 2;
    constexpr int TILE_DW = TLH * TLW * CIG;
    constexpr bool PRELOAD = (NG * NT <= 8);
    constexpr int Ho = H / 2, Wo = W / 2;

    __shared__ int tile[TILE_DW];
    __shared__ float bnl[128];
    __shared__ int8_t lsh[16];
    __shared__ int bsh[PRELOAD ? 1 : NG * NT * 256];

    const int b = blockIdx.z;
    const int py0 = blockIdx.y * 4;
    const int px0 = blockIdx.x * (4 * XL);
    const int ty0 = 2 * py0 - 1;
    const int tx0 = 2 * px0 - 1;
    const int* gin = (const int*)in;

    for (int i = threadIdx.x; i < TILE_DW; i += 256) {
        const int cig = i & (CIG - 1);
        const int rest = i / CIG;
        const int lx = rest % TLW;
        const int ly = rest / TLW;
        const int gy = ty0 + ly, gx = tx0 + lx;
        int v = 0;
        if ((unsigned)gy < (unsigned)H && (unsigned)gx < (unsigned)W)
            v = gin[((b * H + gy) * W + gx) * CIG + cig];
        tile[i] = v;
    }
    if (threadIdx.x < 128) bnl[threadIdx.x] = bnp[layer * 128 + threadIdx.x];
    if (threadIdx.x >= 128 && threadIdx.x < 144)
        lsh[threadIdx.x - 128] = luts[layer * 16 + threadIdx.x - 128];
    if constexpr (!PRELOAD) {
        for (int i = threadIdx.x; i < NG * NT * 256; i += 256) bsh[i] = bfrag[i];
    }

    const int lane = threadIdx.x & 63;
    const int wv = threadIdx.x >> 6;
    v4i breg[PRELOAD ? NG * NT : 1];
    if constexpr (PRELOAD) {
#pragma unroll
        for (int i = 0; i < NG * NT; ++i)
            breg[i] = *(const v4i*)&bfrag[(i * 64 + lane) * 4];
    }
    __syncthreads();

    const int q = lane >> 4;
    const int m = lane & 15;

    const float swv = __uint_as_float(smax[layer]) / 7.0f;
    const float fscale = scales[sin_idx] * swv;
    const float s_relu = scales[srelu_idx];

    const int px_sub = m >> 2;
    const int op = m & 3;
    const int lyb = 2 * wv + (op >> 1);
    const int lxb0 = 2 * px_sub + (op & 1);
    const int py = py0 + wv;

    for (int xs = 0; xs < XL; ++xs) {
        v4i acc[NT];
#pragma unroll
        for (int j = 0; j < NT; ++j) acc[j] = (v4i){0, 0, 0, 0};

#pragma unroll
        for (int g = 0; g < NG; ++g) {
            v4i af;
            if constexpr (CIG == 16) {
                const int ky = (g * 11) >> 5;
                const int kx = g - 3 * ky;
                const int addr = ((lyb + ky) * TLW + (8 * xs + lxb0 + kx)) * 16 + 4 * q;
                af = *(const v4i*)&tile[addr];
            } else if constexpr (CIG == 8) {
                int t = 2 * g + (q >> 1); t = min(t, 8);
                const int ky = (t * 11) >> 5;
                const int kx = t - 3 * ky;
                const int addr = ((lyb + ky) * TLW + (8 * xs + lxb0 + kx)) * 8 + 4 * (q & 1);
                af = *(const v4i*)&tile[addr];
            } else {  // CIG == 4
                int t = 4 * g + q; t = min(t, 8);
                const int ky = (t * 11) >> 5;
                const int kx = t - 3 * ky;
                const int addr = ((lyb + ky) * TLW + (8 * xs + lxb0 + kx)) * 4;
                af = *(const v4i*)&tile[addr];
            }
#pragma unroll
            for (int j = 0; j < NT; ++j) {
                v4i bf;
                if constexpr (PRELOAD) bf = breg[g * NT + j];
                else bf = *(const v4i*)&bsh[((g * NT + j) * 64 + lane) * 4];
                acc[j] = mfma16(af, bf, acc[j]);
            }
        }

        const int px = px0 + 4 * xs + q;
        int8_t* po = out + ((size_t)((b * Ho + py) * Wo + px)) * CO + m;
#pragma unroll
        for (int j = 0; j < NT; ++j) {
            const int co = j * 16 + m;
            const int s = max(max(acc[j][0], acc[j][1]), max(acc[j][2], acc[j][3]));
            const int ri = q_r(s, fscale, bnl[co], bnl[64 + co], s_relu);
            po[j * 16] = lsh[ri];
        }
    }
}

// ---------------------------------------------------------------------------
// Fused tail: L4..L7 (20x40x64, 3x3 SAME) + 1x1 head (64->36) + bias.
// One block per image (16 blocks x 1024 threads). Entire image ping-pongs in
// LDS as zero-padded NHWC [22][42][64]; per-layer B fragments staged to LDS.
// ---------------------------------------------------------------------------
__global__ __launch_bounds__(1024) void k_tail(
    const int8_t* __restrict__ in, const int* __restrict__ qw,
    const float* __restrict__ scales, const unsigned* __restrict__ smax,
    const float* __restrict__ bnp, const int8_t* __restrict__ luts,
    const int* __restrict__ hfrag, const float* __restrict__ b9,
    float* __restrict__ dout)
{
#pragma clang fp contract(off)
    __shared__ int8_t img[2][22 * 42 * 64];   // 2 x 59136 B
    __shared__ int bsh[9216];                 // 36864 B (one layer's B frags)
    __shared__ float bnl[512];                // inv/beta, layers 4..7
    __shared__ int8_t lsh[64];                // requant LUTs, layers 4..7

    const int b = blockIdx.x;
    const int tid = threadIdx.x;
    const int lane = tid & 63;
    const int wv = tid >> 6;                  // 0..15
    const int q = lane >> 4;
    const int m = lane & 15;

    // zero both buffers (borders must stay 0), stage constants
    int* ia = (int*)img;
    for (int i = tid; i < 2 * 22 * 42 * 16; i += 1024) ia[i] = 0;
    for (int i = tid; i < 512; i += 1024) bnl[i] = bnp[512 + i];
    if (tid < 64) lsh[tid] = luts[64 + tid];
    __syncthreads();

    // stage L3 output (NHWC [20][40][64]) into img[0] interior
    const int* gin = (const int*)in;
    int* i0 = (int*)img[0];
    for (int i = tid; i < 12800; i += 1024) {
        const int c = i & 15;
        const int px = (i >> 4) % 40;
        const int y = (i >> 4) / 40;
        i0[((y + 1) * 42 + px + 1) * 16 + c] = gin[((b * 20 + y) * 40 + px) * 16 + c];
    }

    const int bo_[4] = {16128, 25344, 34560, 43776};
    int cur = 0;
    for (int l = 0; l < 4; ++l) {
        __syncthreads();   // prev layer's bsh reads + img writes done
        const int bofs = bo_[l];
        for (int i = tid; i < 9216; i += 1024) bsh[i] = qw[bofs + i];
        __syncthreads();   // bsh ready

        const float swv = __uint_as_float(smax[4 + l]) / 7.0f;
        const float fscale = scales[5 + l] * swv;
        const float s_relu = scales[14 + l];
        const int8_t* imin = img[cur];
        int8_t* imout = img[cur ^ 1];

        // M-tiles: (row y 0..19) x (strip 0..2 of 16 px, px>=40 masked)
        for (int it = wv; it < 60; it += 16) {
            const int y = it / 3;
            const int st = it - 3 * y;
            const int pa = st * 16 + m;       // A row = px (may be >=40: garbage, masked)
            v4i acc[4];
#pragma unroll
            for (int j = 0; j < 4; ++j) acc[j] = (v4i){0, 0, 0, 0};
#pragma unroll
            for (int g = 0; g < 9; ++g) {
                const int ky = (g * 11) >> 5;
                const int kx = g - 3 * ky;
                const v4i af = *(const v4i*)&imin[(((y + ky) * 42) + pa + kx) * 64 + 16 * q];
#pragma unroll
                for (int j = 0; j < 4; ++j) {
                    const v4i bf = *(const v4i*)&bsh[((g * 4 + j) * 64 + lane) * 4];
                    acc[j] = mfma16(af, bf, acc[j]);
                }
            }
#pragma unroll
            for (int j = 0; j < 4; ++j) {
                const int co = j * 16 + m;
                const float inv = bnl[l * 128 + co];
                const float beta = bnl[l * 128 + 64 + co];
#pragma unroll
                for (int r = 0; r < 4; ++r) {
                    const int px = st * 16 + 4 * q + r;
                    if (px < 40) {
                        const int ri = q_r(acc[j][r], fscale, inv, beta, s_relu);
                        imout[((y + 1) * 42 + px + 1) * 64 + co] = lsh[l * 16 + ri];
                    }
                }
            }
        }
        cur ^= 1;
    }
    __syncthreads();

    // head: 1x1 conv 64->36 + bias, fp32 NCHW out
    {
        const float fs = scales[9] * (__uint_as_float(smax[8]) / 7.0f);
        const int8_t* imin = img[cur];
        for (int it = wv; it < 60; it += 16) {
            const int y = it / 3;
            const int st = it - 3 * y;
            const int pa = st * 16 + m;
            const v4i ha = *(const v4i*)&imin[((y + 1) * 42 + pa + 1) * 64 + 16 * q];
#pragma unroll
            for (int nt = 0; nt < 3; ++nt) {
                const v4i hb = *(const v4i*)&hfrag[(nt * 64 + lane) * 4];
                const v4i hacc = mfma16(ha, hb, (v4i){0, 0, 0, 0});
                const int co = nt * 16 + m;
                if (co < 36) {
                    const float bias = b9[co];
#pragma unroll
                    for (int r = 0; r < 4; ++r) {
                        const int px = st * 16 + 4 * q + r;
                        if (px < 40) {
                            float yv = (float)hacc[r] * fs;
                            dout[((size_t)(b * 36 + co)) * 800 + y * 40 + px] = yv + bias;
                        }
                    }
                }
            }
        }
    }
}

// ---------------------------------------------------------------------------
// Launch
// ---------------------------------------------------------------------------
extern "C" void kernel_launch(void* const* d_in, const int* in_sizes, int n_in,
                              void* d_out, int out_size, void* d_ws, size_t ws_size,
                              hipStream_t stream)
{
    const float* x = (const float*)d_in[0];
    const float* w[9];
    for (int i = 0; i < 9; i++) w[i] = (const float*)d_in[1 + i];
    const float* b9 = (const float*)d_in[10];
    const float* bn[8];
    for (int i = 0; i < 8; i++) bn[i] = (const float*)d_in[11 + i];
    const float* scales = (const float*)d_in[19];

    int8_t* base = (int8_t*)d_ws;
    int8_t* bufA = base;                             // 13,107,200 B
    int8_t* bufB = base + 13107200;                  // 13,107,200 B
    int*     qw  = (int*)(base + 26214400);          // 53760 dwords
    unsigned* smax = (unsigned*)(base + 26429440);   // 9
    float*   bnp = (float*)(base + 26429952);        // 1024 floats
    int8_t*  luts = base + 26434048;                 // 144 B

    static const int wn[9] = {432, 4608, 18432, 36864, 36864, 36864, 36864, 36864, 2304};

    hipMemsetAsync(smax, 0, 9 * sizeof(unsigned), stream);

    WPtrs wp;
    for (int i = 0; i < 9; i++) { wp.w[i] = w[i]; wp.n[i] = wn[i]; }
    k_wmax<<<dim3(16, 9), 256, 0, stream>>>(wp, smax);

    PackArgs pa;
    for (int i = 0; i < 9; i++) pa.w[i] = w[i];
    for (int i = 0; i < 8; i++) pa.bn[i] = bn[i];
    pa.sc = scales; pa.smax = smax; pa.qw = qw; pa.bnp = bnp; pa.lut = luts;
    k_pack<<<NB_B + NB_HEAD + NB_BN, 256, 0, stream>>>(pa);

    // L0: fp32 x -> NHWC codes [16][160][320][16] in bufB
    k_conv0<<<dim3(10, 40, 16), 256, 0, stream>>>(
        x, bufB, qw, scales, smax, bnp, luts);

    // L1: CIG=4, CO=32, 160x320 -> 80x160
    k_mconv<4, 32, 160, 320, 4><<<dim3(10, 20, 16), 256, 0, stream>>>(
        bufB, bufA, qw + 256, scales, smax, bnp, luts, 1, 2, 11);
    // L2: CIG=8, CO=64, 80x160 -> 40x80
    k_mconv<8, 64, 80, 160, 2><<<dim3(10, 10, 16), 256, 0, stream>>>(
        bufA, bufB, qw + 1792, scales, smax, bnp, luts, 2, 3, 12);
    // L3: CIG=16, CO=64, 40x80 -> 20x40
    k_mconv<16, 64, 40, 80, 1><<<dim3(10, 5, 16), 256, 0, stream>>>(
        bufB, bufA, qw + 6912, scales, smax, bnp, luts, 3, 4, 13);

    // L4..L7 + head, fully LDS-resident, one block per image
    k_tail<<<16, 1024, 0, stream>>>(
        bufA, qw, scales, smax, bnp, luts, qw + 52992, b9, (float*)d_out);

    (void)in_sizes; (void)n_in; (void)out_size; (void)ws_size;
}